// Round 11
// baseline (118.995 us; speedup 1.0000x reference)
//
#include <hip/hip_runtime.h>

static constexpr int HD   = 128;   // head dim
static constexpr int HH   = 64;    // height
static constexpr int WW   = 64;    // width
static constexpr int ROWS = 2;     // tile rows per block
static constexpr int BLK  = 512;   // 4 threads per pixel (d-quarters)
static constexpr int HALO = ROWS + 2;     // 4 halo rows
static constexpr int DC   = 16;    // d-planes per chunk
static constexpr int NCH  = HD / DC;      // 8 chunks
static constexpr int PSTR = 8;     // uints per pixel in LDS (16 halves)
static constexpr float SCALE = 0.08838834764831845f;  // 128^-0.5

typedef __fp16 h2_t __attribute__((ext_vector_type(2)));

static __device__ __forceinline__ unsigned pk2(float a, float b) {
  h2_t h = __builtin_amdgcn_cvt_pkrtz(a, b);   // v_cvt_pkrtz_f16_f32
  return __builtin_bit_cast(unsigned, h);
}
static __device__ __forceinline__ float lo2f(unsigned u) {
  h2_t h = __builtin_bit_cast(h2_t, u);
  return (float)h[0];                          // fpext -> fuses into v_fma_mix
}
static __device__ __forceinline__ float hi2f(unsigned u) {
  h2_t h = __builtin_bit_cast(h2_t, u);
  return (float)h[1];
}

// fp16 LDS staging, R8 pipeline structure. Unit g (4 planes, 8B) of column ws
// lives at slot g ^ ((ws>>2)&3); implemented on the write side as two
// ds_write_b64 at XOR'd addresses (no data select). Reads: unit qf of column
// cc at slot qf ^ ((cc>>2)&3) -> conflict-minimal b64.
__global__ __launch_bounds__(BLK, 8) void natten3_kernel(
    const float* __restrict__ Q, const float* __restrict__ K,
    const float* __restrict__ V, float* __restrict__ O)
{
  __shared__ unsigned buf[2][HALO * WW * PSTR];   // 2 x 8 KB

  const int tid = threadIdx.x;
  const int qf  = tid & 3;               // d-quarter
  const int px  = tid >> 2;              // 0..127 pixel in tile
  const int w   = px & 63;
  const int pr  = px >> 6;               // tile row 0/1

  // XCD-chunked swizzle: 1024 blocks, 128 consecutive tiles per XCD
  const int bid = blockIdx.x;
  const int swz = (bid & 7) * 128 + (bid >> 3);
  const int b   = swz >> 5;              // image
  const int h0  = (swz & 31) * ROWS;     // tile top row
  const int hh  = h0 + pr;

  const int plane = HH * WW;             // 4096
  const size_t img = (size_t)HD * plane;
  const float* Qb = Q + (size_t)b * img;
  const float* Kb = K + (size_t)b * img;
  const float* Vb = V + (size_t)b * img;
  const int qoff = hh * WW + w;
  const int dq   = 4 * qf;

  // staging map: 512 write-groups = 4 halo rows x 64 ws x 2 half-groups, 1/thread
  const int ws   = tid & 63;
  const int rest = tid >> 6;             // 0..7
  const int is   = rest >> 1;            // halo row 0..3
  const int hg   = rest & 1;             // planes hg*8 .. hg*8+7
  const int grow = min(max(h0 - 1 + is, 0), HH - 1);
  const int sgg  = grow * WW + ws;       // + (c*DC + hg*8 + p)*plane
  const int pairbase = (is * WW + ws) * PSTR + 4 * (hg ^ ((ws >> 3) & 1));
  const int sswp = (ws >> 2) & 1;
  const int offA = pairbase + 2 * sswp;        // unit (planes dstg..+3)
  const int offB = pairbase + 2 * (sswp ^ 1);  // unit (planes dstg+4..+7)
  const int dstg = hg * 8;

  // neighbor LDS offsets (uint units, swizzled)
  int lofs[9];
  #pragma unroll
  for (int dh = 0; dh < 3; ++dh) {
    #pragma unroll
    for (int dw = 0; dw < 3; ++dw) {
      const int cc = min(max(w + dw - 1, 0), WW - 1);
      lofs[dh * 3 + dw] = ((pr + dh) * WW + cc) * PSTR + 2 * (qf ^ ((cc >> 2) & 3));
    }
  }

  // ================= Phase 1: logits =================
  {
    unsigned u0 = pk2(Kb[(dstg + 0) * plane + sgg], Kb[(dstg + 1) * plane + sgg]);
    unsigned u1 = pk2(Kb[(dstg + 2) * plane + sgg], Kb[(dstg + 3) * plane + sgg]);
    unsigned u2 = pk2(Kb[(dstg + 4) * plane + sgg], Kb[(dstg + 5) * plane + sgg]);
    unsigned u3 = pk2(Kb[(dstg + 6) * plane + sgg], Kb[(dstg + 7) * plane + sgg]);
    *(uint2*)&buf[0][offA] = make_uint2(u0, u1);
    *(uint2*)&buf[0][offB] = make_uint2(u2, u3);
  }
  float q[4];
  #pragma unroll
  for (int p = 0; p < 4; ++p) q[p] = Qb[(dq + p) * plane + qoff];
  __syncthreads();

  float logit[9];
  #pragma unroll
  for (int j = 0; j < 9; ++j) logit[j] = 0.0f;

  for (int c = 0; c < NCH; ++c) {
    const int cur = c & 1;
    unsigned un[4];
    float qn[4];
    if (c + 1 < NCH) {                   // issue + pack next chunk early
      const int dbase = (c + 1) * DC * plane + sgg;
      un[0] = pk2(Kb[dbase + (dstg + 0) * plane], Kb[dbase + (dstg + 1) * plane]);
      un[1] = pk2(Kb[dbase + (dstg + 2) * plane], Kb[dbase + (dstg + 3) * plane]);
      un[2] = pk2(Kb[dbase + (dstg + 4) * plane], Kb[dbase + (dstg + 5) * plane]);
      un[3] = pk2(Kb[dbase + (dstg + 6) * plane], Kb[dbase + (dstg + 7) * plane]);
      #pragma unroll
      for (int p = 0; p < 4; ++p)
        qn[p] = Qb[((c + 1) * DC + dq + p) * plane + qoff];
    }
    const unsigned* __restrict__ bc = buf[cur];
    #pragma unroll
    for (int j = 0; j < 9; ++j) {
      const uint2 r = *(const uint2*)&bc[lofs[j]];
      float acc = logit[j];
      acc = fmaf(lo2f(r.x), q[0], acc); acc = fmaf(hi2f(r.x), q[1], acc);
      acc = fmaf(lo2f(r.y), q[2], acc); acc = fmaf(hi2f(r.y), q[3], acc);
      logit[j] = acc;
    }
    if (c + 1 < NCH) {
      *(uint2*)&buf[cur ^ 1][offA] = make_uint2(un[0], un[1]);
      *(uint2*)&buf[cur ^ 1][offB] = make_uint2(un[2], un[3]);
      #pragma unroll
      for (int p = 0; p < 4; ++p) q[p] = qn[p];
    }
    __syncthreads();
  }

  // issue + pack V chunk 0 now; softmax math hides the latency
  unsigned vsu[4];
  {
    vsu[0] = pk2(Vb[(dstg + 0) * plane + sgg], Vb[(dstg + 1) * plane + sgg]);
    vsu[1] = pk2(Vb[(dstg + 2) * plane + sgg], Vb[(dstg + 3) * plane + sgg]);
    vsu[2] = pk2(Vb[(dstg + 4) * plane + sgg], Vb[(dstg + 5) * plane + sgg]);
    vsu[3] = pk2(Vb[(dstg + 6) * plane + sgg], Vb[(dstg + 7) * plane + sgg]);
  }

  // quad-reduce partial logits (lanes 4m..4m+3 share a pixel)
  #pragma unroll
  for (int j = 0; j < 9; ++j) {
    logit[j] += __shfl_xor(logit[j], 1);
    logit[j] += __shfl_xor(logit[j], 2);
  }
  // softmax over 9 (OOB logits = 0 participate in denominator); masks recomputed
  float att[9];
  {
    float msk[9];
    #pragma unroll
    for (int dh = 0; dh < 3; ++dh)
      #pragma unroll
      for (int dw = 0; dw < 3; ++dw) {
        const int j = dh * 3 + dw;
        const int r = hh + dh - 1, c = w + dw - 1;
        msk[j] = (r >= 0 && r < HH && c >= 0 && c < WW) ? 1.0f : 0.0f;
      }
    #pragma unroll
    for (int j = 0; j < 9; ++j) logit[j] = msk[j] * logit[j] * SCALE;
    float m = logit[0];
    #pragma unroll
    for (int j = 1; j < 9; ++j) m = fmaxf(m, logit[j]);
    float Z = 0.0f;
    #pragma unroll
    for (int j = 0; j < 9; ++j) { att[j] = __expf(logit[j] - m); Z += att[j]; }
    const float rZ = 1.0f / Z;
    #pragma unroll
    for (int j = 0; j < 9; ++j) att[j] *= rZ * msk[j];
  }

  // ================= Phase 2: PV =================
  *(uint2*)&buf[0][offA] = make_uint2(vsu[0], vsu[1]);
  *(uint2*)&buf[0][offB] = make_uint2(vsu[2], vsu[3]);
  __syncthreads();

  const size_t obase = ((size_t)b * plane + (size_t)h0 * WW) * HD;
  float oprev[4];
  for (int c = 0; c < NCH; ++c) {
    const int cur = c & 1;
    unsigned un[4];
    if (c + 1 < NCH) {
      const int dbase = (c + 1) * DC * plane + sgg;
      un[0] = pk2(Vb[dbase + (dstg + 0) * plane], Vb[dbase + (dstg + 1) * plane]);
      un[1] = pk2(Vb[dbase + (dstg + 2) * plane], Vb[dbase + (dstg + 3) * plane]);
      un[2] = pk2(Vb[dbase + (dstg + 4) * plane], Vb[dbase + (dstg + 5) * plane]);
      un[3] = pk2(Vb[dbase + (dstg + 6) * plane], Vb[dbase + (dstg + 7) * plane]);
    }
    float o0 = 0.f, o1 = 0.f, o2 = 0.f, o3 = 0.f;
    const unsigned* __restrict__ bc = buf[cur];
    #pragma unroll
    for (int j = 0; j < 9; ++j) {
      const uint2 r = *(const uint2*)&bc[lofs[j]];
      const float a = att[j];
      o0 = fmaf(lo2f(r.x), a, o0); o1 = fmaf(hi2f(r.x), a, o1);
      o2 = fmaf(lo2f(r.y), a, o2); o3 = fmaf(hi2f(r.y), a, o3);
    }
    if (c & 1) {
      // paired writeout: quad covers one full 128B sector of its pixel
      const size_t oa = obase + (size_t)px * HD + (size_t)(c - 1) * DC + dq;
      *(float4*)&O[oa]      = make_float4(oprev[0], oprev[1], oprev[2], oprev[3]);
      *(float4*)&O[oa + DC] = make_float4(o0, o1, o2, o3);
    } else {
      oprev[0] = o0; oprev[1] = o1; oprev[2] = o2; oprev[3] = o3;
    }
    if (c + 1 < NCH) {
      *(uint2*)&buf[cur ^ 1][offA] = make_uint2(un[0], un[1]);
      *(uint2*)&buf[cur ^ 1][offB] = make_uint2(un[2], un[3]);
      __syncthreads();
    }
  }
}

extern "C" void kernel_launch(void* const* d_in, const int* in_sizes, int n_in,
                              void* d_out, int out_size, void* d_ws, size_t ws_size,
                              hipStream_t stream) {
  const float* q = (const float*)d_in[0];
  const float* k = (const float*)d_in[1];
  const float* v = (const float*)d_in[2];
  float* o = (float*)d_out;
  const int nblocks = 32 * (HH / ROWS);   // 1024
  natten3_kernel<<<dim3(nblocks), dim3(BLK), 0, stream>>>(q, k, v, o);
}

// Round 12
// 53.309 us; speedup vs baseline: 2.2322x; 2.2322x over previous
//
#include <hip/hip_runtime.h>

static constexpr int HD   = 128;   // head dim
static constexpr int HH   = 64;    // height
static constexpr int WW   = 64;    // width
static constexpr int ROWS = 2;     // tile rows per block
static constexpr int BLK  = 512;   // 4 threads per pixel (d-quarters)
static constexpr int HALO = ROWS + 2;     // 4 halo rows
static constexpr int DC   = 16;    // d-planes per chunk
static constexpr int NCH  = HD / DC;      // 8 chunks
static constexpr int PSTR = 8;     // uints per pixel in LDS (16 halves)
static constexpr float SCALE = 0.08838834764831845f;  // 128^-0.5

typedef __fp16 h2_t __attribute__((ext_vector_type(2)));

static __device__ __forceinline__ unsigned pk2(float a, float b) {
  h2_t h = __builtin_amdgcn_cvt_pkrtz(a, b);   // v_cvt_pkrtz_f16_f32
  return __builtin_bit_cast(unsigned, h);
}
static __device__ __forceinline__ float lo2f(unsigned u) {
  h2_t h = __builtin_bit_cast(h2_t, u);
  return (float)h[0];                          // fpext -> fuses into v_fma_mix
}
static __device__ __forceinline__ float hi2f(unsigned u) {
  h2_t h = __builtin_bit_cast(h2_t, u);
  return (float)h[1];
}

// fp16 LDS staging, R8 pipeline structure. Unit g (4 planes, 8B) of column ws
// lives at slot g ^ ((ws>>2)&3); write side = two ds_write_b64 at XOR'd
// addresses (no data select). Reads: unit qf of column cc at slot
// qf ^ ((cc>>2)&3) -> conflict-minimal b64.
// launch_bounds(512,4): R11's (512,8) forced a 64-VGPR cap -> scratch spills
// (WRITE_SIZE 66->172MB, dur 3x). Never force occupancy beyond verified fit.
__global__ __launch_bounds__(BLK, 4) void natten3_kernel(
    const float* __restrict__ Q, const float* __restrict__ K,
    const float* __restrict__ V, float* __restrict__ O)
{
  __shared__ unsigned buf[2][HALO * WW * PSTR];   // 2 x 8 KB

  const int tid = threadIdx.x;
  const int qf  = tid & 3;               // d-quarter
  const int px  = tid >> 2;              // 0..127 pixel in tile
  const int w   = px & 63;
  const int pr  = px >> 6;               // tile row 0/1

  // XCD-chunked swizzle: 1024 blocks, 128 consecutive tiles per XCD
  const int bid = blockIdx.x;
  const int swz = (bid & 7) * 128 + (bid >> 3);
  const int b   = swz >> 5;              // image
  const int h0  = (swz & 31) * ROWS;     // tile top row
  const int hh  = h0 + pr;

  const int plane = HH * WW;             // 4096
  const size_t img = (size_t)HD * plane;
  const float* Qb = Q + (size_t)b * img;
  const float* Kb = K + (size_t)b * img;
  const float* Vb = V + (size_t)b * img;
  const int qoff = hh * WW + w;
  const int dq   = 4 * qf;

  // staging map: 512 write-groups = 4 halo rows x 64 ws x 2 half-groups, 1/thread
  const int ws   = tid & 63;
  const int rest = tid >> 6;             // 0..7
  const int is   = rest >> 1;            // halo row 0..3
  const int hg   = rest & 1;             // planes hg*8 .. hg*8+7
  const int grow = min(max(h0 - 1 + is, 0), HH - 1);
  const int sgg  = grow * WW + ws;       // + (c*DC + hg*8 + p)*plane
  const int pairbase = (is * WW + ws) * PSTR + 4 * (hg ^ ((ws >> 3) & 1));
  const int sswp = (ws >> 2) & 1;
  const int offA = pairbase + 2 * sswp;        // unit (planes dstg..+3)
  const int offB = pairbase + 2 * (sswp ^ 1);  // unit (planes dstg+4..+7)
  const int dstg = hg * 8;

  // neighbor LDS offsets (uint units, swizzled)
  int lofs[9];
  #pragma unroll
  for (int dh = 0; dh < 3; ++dh) {
    #pragma unroll
    for (int dw = 0; dw < 3; ++dw) {
      const int cc = min(max(w + dw - 1, 0), WW - 1);
      lofs[dh * 3 + dw] = ((pr + dh) * WW + cc) * PSTR + 2 * (qf ^ ((cc >> 2) & 3));
    }
  }

  // ================= Phase 1: logits =================
  {
    unsigned u0 = pk2(Kb[(dstg + 0) * plane + sgg], Kb[(dstg + 1) * plane + sgg]);
    unsigned u1 = pk2(Kb[(dstg + 2) * plane + sgg], Kb[(dstg + 3) * plane + sgg]);
    unsigned u2 = pk2(Kb[(dstg + 4) * plane + sgg], Kb[(dstg + 5) * plane + sgg]);
    unsigned u3 = pk2(Kb[(dstg + 6) * plane + sgg], Kb[(dstg + 7) * plane + sgg]);
    *(uint2*)&buf[0][offA] = make_uint2(u0, u1);
    *(uint2*)&buf[0][offB] = make_uint2(u2, u3);
  }
  float q[4];
  #pragma unroll
  for (int p = 0; p < 4; ++p) q[p] = Qb[(dq + p) * plane + qoff];
  __syncthreads();

  float logit[9];
  #pragma unroll
  for (int j = 0; j < 9; ++j) logit[j] = 0.0f;

  for (int c = 0; c < NCH; ++c) {
    const int cur = c & 1;
    unsigned un[4];
    float qn[4];
    if (c + 1 < NCH) {                   // issue + pack next chunk early
      const int dbase = (c + 1) * DC * plane + sgg;
      un[0] = pk2(Kb[dbase + (dstg + 0) * plane], Kb[dbase + (dstg + 1) * plane]);
      un[1] = pk2(Kb[dbase + (dstg + 2) * plane], Kb[dbase + (dstg + 3) * plane]);
      un[2] = pk2(Kb[dbase + (dstg + 4) * plane], Kb[dbase + (dstg + 5) * plane]);
      un[3] = pk2(Kb[dbase + (dstg + 6) * plane], Kb[dbase + (dstg + 7) * plane]);
      #pragma unroll
      for (int p = 0; p < 4; ++p)
        qn[p] = Qb[((c + 1) * DC + dq + p) * plane + qoff];
    }
    const unsigned* __restrict__ bc = buf[cur];
    #pragma unroll
    for (int j = 0; j < 9; ++j) {
      const uint2 r = *(const uint2*)&bc[lofs[j]];
      float acc = logit[j];
      acc = fmaf(lo2f(r.x), q[0], acc); acc = fmaf(hi2f(r.x), q[1], acc);
      acc = fmaf(lo2f(r.y), q[2], acc); acc = fmaf(hi2f(r.y), q[3], acc);
      logit[j] = acc;
    }
    if (c + 1 < NCH) {
      *(uint2*)&buf[cur ^ 1][offA] = make_uint2(un[0], un[1]);
      *(uint2*)&buf[cur ^ 1][offB] = make_uint2(un[2], un[3]);
      #pragma unroll
      for (int p = 0; p < 4; ++p) q[p] = qn[p];
    }
    __syncthreads();
  }

  // issue + pack V chunk 0 now; softmax math hides the latency
  unsigned vsu[4];
  {
    vsu[0] = pk2(Vb[(dstg + 0) * plane + sgg], Vb[(dstg + 1) * plane + sgg]);
    vsu[1] = pk2(Vb[(dstg + 2) * plane + sgg], Vb[(dstg + 3) * plane + sgg]);
    vsu[2] = pk2(Vb[(dstg + 4) * plane + sgg], Vb[(dstg + 5) * plane + sgg]);
    vsu[3] = pk2(Vb[(dstg + 6) * plane + sgg], Vb[(dstg + 7) * plane + sgg]);
  }

  // quad-reduce partial logits (lanes 4m..4m+3 share a pixel)
  #pragma unroll
  for (int j = 0; j < 9; ++j) {
    logit[j] += __shfl_xor(logit[j], 1);
    logit[j] += __shfl_xor(logit[j], 2);
  }
  // softmax over 9 (OOB logits = 0 participate in denominator); masks recomputed
  float att[9];
  {
    float msk[9];
    #pragma unroll
    for (int dh = 0; dh < 3; ++dh)
      #pragma unroll
      for (int dw = 0; dw < 3; ++dw) {
        const int j = dh * 3 + dw;
        const int r = hh + dh - 1, c = w + dw - 1;
        msk[j] = (r >= 0 && r < HH && c >= 0 && c < WW) ? 1.0f : 0.0f;
      }
    #pragma unroll
    for (int j = 0; j < 9; ++j) logit[j] = msk[j] * logit[j] * SCALE;
    float m = logit[0];
    #pragma unroll
    for (int j = 1; j < 9; ++j) m = fmaxf(m, logit[j]);
    float Z = 0.0f;
    #pragma unroll
    for (int j = 0; j < 9; ++j) { att[j] = __expf(logit[j] - m); Z += att[j]; }
    const float rZ = 1.0f / Z;
    #pragma unroll
    for (int j = 0; j < 9; ++j) att[j] *= rZ * msk[j];
  }

  // ================= Phase 2: PV =================
  *(uint2*)&buf[0][offA] = make_uint2(vsu[0], vsu[1]);
  *(uint2*)&buf[0][offB] = make_uint2(vsu[2], vsu[3]);
  __syncthreads();

  const size_t obase = ((size_t)b * plane + (size_t)h0 * WW) * HD;
  float oprev[4];
  for (int c = 0; c < NCH; ++c) {
    const int cur = c & 1;
    unsigned un[4];
    if (c + 1 < NCH) {
      const int dbase = (c + 1) * DC * plane + sgg;
      un[0] = pk2(Vb[dbase + (dstg + 0) * plane], Vb[dbase + (dstg + 1) * plane]);
      un[1] = pk2(Vb[dbase + (dstg + 2) * plane], Vb[dbase + (dstg + 3) * plane]);
      un[2] = pk2(Vb[dbase + (dstg + 4) * plane], Vb[dbase + (dstg + 5) * plane]);
      un[3] = pk2(Vb[dbase + (dstg + 6) * plane], Vb[dbase + (dstg + 7) * plane]);
    }
    float o0 = 0.f, o1 = 0.f, o2 = 0.f, o3 = 0.f;
    const unsigned* __restrict__ bc = buf[cur];
    #pragma unroll
    for (int j = 0; j < 9; ++j) {
      const uint2 r = *(const uint2*)&bc[lofs[j]];
      const float a = att[j];
      o0 = fmaf(lo2f(r.x), a, o0); o1 = fmaf(hi2f(r.x), a, o1);
      o2 = fmaf(lo2f(r.y), a, o2); o3 = fmaf(hi2f(r.y), a, o3);
    }
    if (c & 1) {
      // paired writeout: quad covers one full 128B sector of its pixel
      const size_t oa = obase + (size_t)px * HD + (size_t)(c - 1) * DC + dq;
      *(float4*)&O[oa]      = make_float4(oprev[0], oprev[1], oprev[2], oprev[3]);
      *(float4*)&O[oa + DC] = make_float4(o0, o1, o2, o3);
    } else {
      oprev[0] = o0; oprev[1] = o1; oprev[2] = o2; oprev[3] = o3;
    }
    if (c + 1 < NCH) {
      *(uint2*)&buf[cur ^ 1][offA] = make_uint2(un[0], un[1]);
      *(uint2*)&buf[cur ^ 1][offB] = make_uint2(un[2], un[3]);
      __syncthreads();
    }
  }
}

extern "C" void kernel_launch(void* const* d_in, const int* in_sizes, int n_in,
                              void* d_out, int out_size, void* d_ws, size_t ws_size,
                              hipStream_t stream) {
  const float* q = (const float*)d_in[0];
  const float* k = (const float*)d_in[1];
  const float* v = (const float*)d_in[2];
  float* o = (float*)d_out;
  const int nblocks = 32 * (HH / ROWS);   // 1024
  natten3_kernel<<<dim3(nblocks), dim3(BLK), 0, stream>>>(q, k, v, o);
}

// Round 13
// 49.247 us; speedup vs baseline: 2.4163x; 1.0825x over previous
//
#include <hip/hip_runtime.h>

static constexpr int HD   = 128;   // head dim
static constexpr int HH   = 64;    // height
static constexpr int WW   = 64;    // width
static constexpr int ROWS = 2;     // tile rows per block
static constexpr int BLK  = 512;   // 4 threads per pixel (d-quarters)
static constexpr int HALO = ROWS + 2;     // 4 halo rows
static constexpr int DC   = 16;    // d-planes per chunk
static constexpr int NCH  = HD / DC;      // 8 K-chunks (and 8 V-chunks)
static constexpr int NT   = 16;    // total chunks staged: 8 K then 8 V
static constexpr int PSTR = 66;    // floats per (is,p) row: 64 + 2 pad ->
                                   // read banks (8qf+2pp+cc)%32 hit each bank
                                   // exactly 2x per wave = free (m136)
static constexpr int SLOT = HALO * DC * PSTR;   // 4224 floats per chunk slot
static constexpr float SCALE = 0.08838834764831845f;  // 128^-0.5

#define MEMFENCE asm volatile("" ::: "memory")
#define VMWAIT(N) asm volatile("s_waitcnt vmcnt(" #N ")" ::: "memory")

// 2-deep staging pipeline, un-sinkable: global_load_lds (no dest regs) into a
// triple-buffered plane-major LDS tile; raw s_barrier + counted vmcnt (never 0
// mid-loop). Per K-segment FIFO: [stage c+1 (8)][q_c (4)] -> entry wait
// vmcnt(12) retires stage c; q issued BEFORE stage behind a fence so the
// compiler's own q-wait (vmcnt(20)) forces nothing. V loop: vmcnt(8); final
// segment drains vmcnt(0). R7's register 2-deep died by load-sinking (VGPR 32
// proved it); LDS-destination loads cannot sink.
__global__ __launch_bounds__(BLK, 4) void natten3_kernel(
    const float* __restrict__ Q, const float* __restrict__ K,
    const float* __restrict__ V, float* __restrict__ O)
{
  __shared__ float buf[3][SLOT];   // 50688 B -> 3 blocks/CU

  const int tid  = threadIdx.x;
  const int lane = tid & 63;
  const int wid  = tid >> 6;             // 0..7
  const int qf   = tid & 3;              // d-quarter
  const int px   = tid >> 2;             // 0..127 pixel in tile
  const int w    = px & 63;
  const int pr   = px >> 6;              // tile row 0/1

  // XCD-chunked swizzle: 1024 blocks, 128 consecutive tiles per XCD
  const int bid = blockIdx.x;
  const int swz = (bid & 7) * 128 + (bid >> 3);
  const int b   = swz >> 5;              // image
  const int h0  = (swz & 31) * ROWS;     // tile top row
  const int hh  = h0 + pr;

  const int plane = HH * WW;             // 4096
  const size_t img = (size_t)HD * plane;
  const float* Qb = Q + (size_t)b * img;
  const float* Kb = K + (size_t)b * img;
  const float* Vb = V + (size_t)b * img;
  const int qoff = hh * WW + w;
  const int dq   = 4 * qf;

  // staging map: 64 (is,p) rows per chunk, 8 per wave (idx = wid*8+k).
  // global: lane i -> float ws=i of row grow(is), plane p  (coalesced 256B)
  // lds   : slot + idx*PSTR + lane                         (linear, lane*4B)
  int gofs[8];
  #pragma unroll
  for (int k = 0; k < 8; ++k) {
    const int idx = wid * 8 + k, is = idx >> 4, p = idx & 15;
    const int grow = min(max(h0 - 1 + is, 0), HH - 1);
    gofs[k] = p * plane + grow * WW + lane;
  }
  const int lbase = wid * 8 * PSTR;      // + k*PSTR per k

  // read offsets: neighbor j at plane dq+pp -> lofs[j] + pp*PSTR
  int lofs[9];
  #pragma unroll
  for (int dh = 0; dh < 3; ++dh)
    #pragma unroll
    for (int dw = 0; dw < 3; ++dw) {
      const int cc = min(max(w + dw - 1, 0), WW - 1);
      lofs[dh * 3 + dw] = ((pr + dh) * DC + dq) * PSTR + cc;
    }

  // stage chunk t (0..7 = K chunks, 8..15 = V chunks) into slot t%3
  auto STAGE = [&](int t) {
    const float* cb = (t < NCH ? Kb : Vb) + ((t & 7) * DC) * plane;
    float* sb = &buf[t % 3][lbase];
    #pragma unroll
    for (int k = 0; k < 8; ++k) {
      __builtin_amdgcn_global_load_lds(
          (const __attribute__((address_space(1))) void*)(cb + gofs[k]),
          (__attribute__((address_space(3))) void*)(sb + k * PSTR), 4, 0, 0);
    }
  };

  // ---- prologue: FIFO [stage0 (8)][q0 (4)][stage1 (8)]
  STAGE(0);
  float q[4];
  #pragma unroll
  for (int p = 0; p < 4; ++p) q[p] = Qb[(dq + p) * plane + qoff];
  MEMFENCE;
  STAGE(1);

  float logit[9];
  #pragma unroll
  for (int j = 0; j < 9; ++j) logit[j] = 0.0f;

  // ================= K segments =================
  #pragma unroll 1
  for (int c = 0; c < NCH; ++c) {
    VMWAIT(12);                          // retire stage c (mine)
    __builtin_amdgcn_s_barrier();        // all waves' stage c landed; seals
    MEMFENCE;                            //   reads of slot (c+2)%3
    float qn[4];
    if (c + 1 < NCH) {
      #pragma unroll
      for (int p = 0; p < 4; ++p)
        qn[p] = Qb[((c + 1) * DC + dq + p) * plane + qoff];
    }
    MEMFENCE;                            // pin q before stage in FIFO
    STAGE(c + 2);                        // c+2 <= 9: chunks 8,9 are V0,V1
    const float* __restrict__ bc = &buf[c % 3][0];
    #pragma unroll
    for (int j = 0; j < 9; ++j) {
      float acc = logit[j];
      acc = fmaf(q[0], bc[lofs[j]], acc);
      acc = fmaf(q[1], bc[lofs[j] + PSTR], acc);
      acc = fmaf(q[2], bc[lofs[j] + 2 * PSTR], acc);
      acc = fmaf(q[3], bc[lofs[j] + 3 * PSTR], acc);
      logit[j] = acc;
    }
    if (c + 1 < NCH) {
      #pragma unroll
      for (int p = 0; p < 4; ++p) q[p] = qn[p];
    }
  }

  // ---- softmax (pure reg math; V0/V1 already in flight)
  #pragma unroll
  for (int j = 0; j < 9; ++j) {
    logit[j] += __shfl_xor(logit[j], 1);
    logit[j] += __shfl_xor(logit[j], 2);
  }
  float att[9];
  {
    float msk[9];
    #pragma unroll
    for (int dh = 0; dh < 3; ++dh)
      #pragma unroll
      for (int dw = 0; dw < 3; ++dw) {
        const int j = dh * 3 + dw;
        const int r = hh + dh - 1, c = w + dw - 1;
        msk[j] = (r >= 0 && r < HH && c >= 0 && c < WW) ? 1.0f : 0.0f;
      }
    #pragma unroll
    for (int j = 0; j < 9; ++j) logit[j] = msk[j] * logit[j] * SCALE;
    float m = logit[0];
    #pragma unroll
    for (int j = 1; j < 9; ++j) m = fmaxf(m, logit[j]);
    float Z = 0.0f;
    #pragma unroll
    for (int j = 0; j < 9; ++j) { att[j] = __expf(logit[j] - m); Z += att[j]; }
    const float rZ = 1.0f / Z;
    #pragma unroll
    for (int j = 0; j < 9; ++j) att[j] *= rZ * msk[j];
  }

  // ================= V segments =================
  const size_t obase = ((size_t)b * plane + (size_t)h0 * WW) * HD;
  float oprev[4];
  #pragma unroll 1
  for (int t = NCH; t < NT - 1; ++t) {   // t = 8..14
    VMWAIT(8);                           // retire stage t (stores may also drain)
    __builtin_amdgcn_s_barrier();
    MEMFENCE;
    if (t + 2 < NT) STAGE(t + 2);
    const float* __restrict__ bc = &buf[t % 3][0];
    float o0 = 0.f, o1 = 0.f, o2 = 0.f, o3 = 0.f;
    #pragma unroll
    for (int j = 0; j < 9; ++j) {
      const float a = att[j];
      o0 = fmaf(a, bc[lofs[j]], o0);
      o1 = fmaf(a, bc[lofs[j] + PSTR], o1);
      o2 = fmaf(a, bc[lofs[j] + 2 * PSTR], o2);
      o3 = fmaf(a, bc[lofs[j] + 3 * PSTR], o3);
    }
    const int lc = t - NCH;              // 0..6 here
    if (lc & 1) {                        // paired 128B-sector writeout
      const size_t oa = obase + (size_t)px * HD + (size_t)(lc - 1) * DC + dq;
      *(float4*)&O[oa]      = make_float4(oprev[0], oprev[1], oprev[2], oprev[3]);
      *(float4*)&O[oa + DC] = make_float4(o0, o1, o2, o3);
    } else {
      oprev[0] = o0; oprev[1] = o1; oprev[2] = o2; oprev[3] = o3;
    }
  }
  // ---- final segment t = 15 (drain)
  {
    VMWAIT(0);
    __builtin_amdgcn_s_barrier();
    MEMFENCE;
    const float* __restrict__ bc = &buf[(NT - 1) % 3][0];
    float o0 = 0.f, o1 = 0.f, o2 = 0.f, o3 = 0.f;
    #pragma unroll
    for (int j = 0; j < 9; ++j) {
      const float a = att[j];
      o0 = fmaf(a, bc[lofs[j]], o0);
      o1 = fmaf(a, bc[lofs[j] + PSTR], o1);
      o2 = fmaf(a, bc[lofs[j] + 2 * PSTR], o2);
      o3 = fmaf(a, bc[lofs[j] + 3 * PSTR], o3);
    }
    const size_t oa = obase + (size_t)px * HD + (size_t)6 * DC + dq;
    *(float4*)&O[oa]      = make_float4(oprev[0], oprev[1], oprev[2], oprev[3]);
    *(float4*)&O[oa + DC] = make_float4(o0, o1, o2, o3);
  }
}

extern "C" void kernel_launch(void* const* d_in, const int* in_sizes, int n_in,
                              void* d_out, int out_size, void* d_ws, size_t ws_size,
                              hipStream_t stream) {
  const float* q = (const float*)d_in[0];
  const float* k = (const float*)d_in[1];
  const float* v = (const float*)d_in[2];
  float* o = (float*)d_out;
  const int nblocks = 32 * (HH / ROWS);   // 1024
  natten3_kernel<<<dim3(nblocks), dim3(BLK), 0, stream>>>(q, k, v, o);
}